// Round 7
// baseline (348.433 us; speedup 1.0000x reference)
//
#include <hip/hip_runtime.h>

// ---------------------------------------------------------------------------
// TransD-style scoring:
//   score[b] = || rp*(hp.h) + sum(h) + r - rp*(tp.t) - sum(t) ||^2
// Algebraic reduction: with a = hp.h - tp.t, c = sum(h) - sum(t):
//   score = a^2*S_pp + c^2*D + S_rr + 2ac*S_p + 2a*S_pr + 2c*S_r
// Pass 1: per-node (sum, dot). Pass 2: per-relation sums. Pass 3: O(1) score.
//
// Kept from R5/R6 (measured wins): he/hep normal loads (IC-resident,
// FETCH==te/tep footprint confirms), te/tep non-temporal (pure HBM stream,
// no IC allocation); even/odd wave interleave keeps both memory paths
// concurrently active.
// R7 (new): reduction moved OFF the DS pipe. 16 lanes/row, 4 rows/wave,
// 2 float4/lane/table; row reduction via DPP row_shr adds (pure VALU,
// 4 SIMD pipes/CU) instead of 10 ds_bpermute ops on the single shared DS
// pipe (~20 DS-cyc/wave > 12.4 cyc/wave retire budget at 97us). Wave count
// also halves (100k vs 200k).
// ---------------------------------------------------------------------------

#define ENT_DIM 128

typedef float f4_t __attribute__((ext_vector_type(4)));

__device__ __forceinline__ float4 ldg_nt4(const float* p) {
    f4_t v = __builtin_nontemporal_load((const f4_t*)p);
    return make_float4(v.x, v.y, v.z, v.w);
}

// DPP 16-lane inclusive-scan sum: after this, lane (l%16)==15 holds the sum
// of its 16-lane row. row_shr:N with bound_ctrl=1 -> invalid lanes read 0.
__device__ __forceinline__ float dpp16_row_sum(float x) {
    int t;
    t = __builtin_amdgcn_update_dpp(0, __float_as_int(x), 0x111, 0xF, 0xF, true);
    x += __int_as_float(t);   // += lane-1
    t = __builtin_amdgcn_update_dpp(0, __float_as_int(x), 0x112, 0xF, 0xF, true);
    x += __int_as_float(t);   // += lane-2
    t = __builtin_amdgcn_update_dpp(0, __float_as_int(x), 0x114, 0xF, 0xF, true);
    x += __int_as_float(t);   // += lane-4
    t = __builtin_amdgcn_update_dpp(0, __float_as_int(x), 0x118, 0xF, 0xF, true);
    x += __int_as_float(t);   // += lane-8
    return x;
}

// Pass 1: per-node (sum, dot) for head and tail tables.
// One wave = 4 rows of ONE stream (head or tail). 16 lanes/row, each lane
// loads 2 float4 from its row (cols l and l+16). Even waves -> head quads
// (normal loads, IC path); odd waves -> tail quads (nt loads, HBM path).
// Reduction: DPP row_shr chain, zero DS-pipe traffic. Lane 15 of each row
// stores the row's (sum, dot).
__global__ void node_stats_kernel(const float* __restrict__ he,
                                  const float* __restrict__ hep,
                                  const float* __restrict__ te,
                                  const float* __restrict__ tep,
                                  float2* __restrict__ hstats,
                                  float2* __restrict__ tstats,
                                  int n_nodes) {
    const int wave  = (blockIdx.x * blockDim.x + threadIdx.x) >> 6;
    const int lane  = threadIdx.x & 63;
    const int sub   = lane >> 4;     // row within the quad: 0..3
    const int l     = lane & 15;     // float4 slot within the row half
    const int nquads = (n_nodes + 3) >> 2;
    if (wave >= 2 * nquads) return;

    const int is_tail = wave & 1;    // wave-uniform stream select
    const int quad    = wave >> 1;
    const int node    = quad * 4 + sub;
    const bool valid  = node < n_nodes;

    float s = 0.f, d = 0.f;
    if (valid) {
        float4 v0, v1, p0, p1;
        if (!is_tail) {
            // Head tables: normal loads -> IC-resident.
            const float4* vr = (const float4*)(he  + (size_t)node * ENT_DIM);
            const float4* pr = (const float4*)(hep + (size_t)node * ENT_DIM);
            v0 = vr[l]; v1 = vr[l + 16];
            p0 = pr[l]; p1 = pr[l + 16];
        } else {
            // Tail tables: non-temporal -> pure HBM stream, no IC allocation.
            const float* vr = te  + (size_t)node * ENT_DIM;
            const float* pr = tep + (size_t)node * ENT_DIM;
            v0 = ldg_nt4(vr + 4 * l); v1 = ldg_nt4(vr + 4 * (l + 16));
            p0 = ldg_nt4(pr + 4 * l); p1 = ldg_nt4(pr + 4 * (l + 16));
        }
        s = ((v0.x + v0.y) + (v0.z + v0.w)) + ((v1.x + v1.y) + (v1.z + v1.w));
        d = v0.x * p0.x + v0.y * p0.y + v0.z * p0.z + v0.w * p0.w
          + v1.x * p1.x + v1.y * p1.y + v1.z * p1.z + v1.w * p1.w;
    }

    s = dpp16_row_sum(s);
    d = dpp16_row_sum(d);

    if (l == 15 && valid) {
        float2* st = is_tail ? tstats : hstats;
        st[node] = make_float2(s, d);
    }
}

// Pass 2: per-relation sums. One wave per relation (only 500).
__global__ void rel_stats_kernel(const float* __restrict__ re,
                                 const float* __restrict__ rep,
                                 float* __restrict__ rstats, int n_rels) {
    const int wave = (blockIdx.x * blockDim.x + threadIdx.x) >> 6;
    const int lane = threadIdx.x & 63;
    if (wave >= n_rels) return;

    const float2 r = ((const float2*)(re  + (size_t)wave * ENT_DIM))[lane];
    const float2 p = ((const float2*)(rep + (size_t)wave * ENT_DIM))[lane];
    float s_pp = p.x * p.x + p.y * p.y;
    float s_p  = p.x + p.y;
    float s_pr = p.x * r.x + p.y * r.y;
    float s_r  = r.x + r.y;
    float s_rr = r.x * r.x + r.y * r.y;
    #pragma unroll
    for (int off = 32; off >= 1; off >>= 1) {
        s_pp += __shfl_xor(s_pp, off, 64);
        s_p  += __shfl_xor(s_p,  off, 64);
        s_pr += __shfl_xor(s_pr, off, 64);
        s_r  += __shfl_xor(s_r,  off, 64);
        s_rr += __shfl_xor(s_rr, off, 64);
    }
    if (lane == 0) {
        float* o = rstats + (size_t)wave * 8;   // 32B stride per relation
        o[0] = s_pp; o[1] = s_p; o[2] = s_pr; o[3] = s_r; o[4] = s_rr;
    }
}

// Pass 3 (frozen at R2 config): 2 batch elements per thread; int2 idx loads;
// rstats in LDS stride-9 (random ri covers all 32 banks); 4 independent
// L2-resident 8B gathers in flight per thread.
__global__ void score_kernel(const int* __restrict__ hidx,
                             const int* __restrict__ tidx,
                             const int* __restrict__ ridx,
                             const float2* __restrict__ hstats,
                             const float2* __restrict__ tstats,
                             const float* __restrict__ rstats,
                             float* __restrict__ out, int B, int n_rels) {
    extern __shared__ float rs[];   // n_rels * 9 floats
    for (int i = threadIdx.x; i < n_rels * 2; i += blockDim.x) {
        const float4 v = ((const float4*)rstats)[i];
        const int base = (i >> 1) * 9 + (i & 1) * 4;
        rs[base]     = v.x;
        rs[base + 1] = v.y;
        rs[base + 2] = v.z;
        rs[base + 3] = v.w;
    }
    __syncthreads();

    const int g  = blockIdx.x * blockDim.x + threadIdx.x;
    const int b0 = 2 * g;
    if (b0 >= B) return;

    if (b0 + 1 < B) {
        const int2 hi = ((const int2*)hidx)[g];
        const int2 ti = ((const int2*)tidx)[g];
        const int2 ri = ((const int2*)ridx)[g];
        const float2 hs0 = hstats[hi.x];
        const float2 hs1 = hstats[hi.y];
        const float2 ts0 = tstats[ti.x];
        const float2 ts1 = tstats[ti.y];

        const float c0 = hs0.x - ts0.x, a0 = hs0.y - ts0.y;
        const float c1 = hs1.x - ts1.x, a1 = hs1.y - ts1.y;
        const float* q0 = rs + ri.x * 9;
        const float* q1 = rs + ri.y * 9;
        const float sc0 = a0 * a0 * q0[0] + c0 * c0 * (float)ENT_DIM + q0[4]
                        + 2.0f * (a0 * c0 * q0[1] + a0 * q0[2] + c0 * q0[3]);
        const float sc1 = a1 * a1 * q1[0] + c1 * c1 * (float)ENT_DIM + q1[4]
                        + 2.0f * (a1 * c1 * q1[1] + a1 * q1[2] + c1 * q1[3]);
        ((float2*)out)[g] = make_float2(sc0, sc1);
    } else {
        const int hi = hidx[b0], ti = tidx[b0], ri = ridx[b0];
        const float2 hs = hstats[hi];
        const float2 ts = tstats[ti];
        const float c = hs.x - ts.x, a = hs.y - ts.y;
        const float* q = rs + ri * 9;
        out[b0] = a * a * q[0] + c * c * (float)ENT_DIM + q[4]
                + 2.0f * (a * c * q[1] + a * q[2] + c * q[3]);
    }
}

// Fallback (only if ws_size is too small): direct wave-per-element compute.
__global__ void direct_kernel(const float* __restrict__ he, const float* __restrict__ hep,
                              const float* __restrict__ te, const float* __restrict__ tep,
                              const float* __restrict__ re, const float* __restrict__ rep,
                              const int* __restrict__ hidx, const int* __restrict__ tidx,
                              const int* __restrict__ ridx,
                              float* __restrict__ out, int B) {
    const int wave = (blockIdx.x * blockDim.x + threadIdx.x) >> 6;
    const int lane = threadIdx.x & 63;
    if (wave >= B) return;
    const int hi = hidx[wave], ti = tidx[wave], ri = ridx[wave];
    const float2 h  = ((const float2*)(he  + (size_t)hi * ENT_DIM))[lane];
    const float2 hp = ((const float2*)(hep + (size_t)hi * ENT_DIM))[lane];
    const float2 t  = ((const float2*)(te  + (size_t)ti * ENT_DIM))[lane];
    const float2 tp = ((const float2*)(tep + (size_t)ti * ENT_DIM))[lane];
    const float2 r  = ((const float2*)(re  + (size_t)ri * ENT_DIM))[lane];
    const float2 rp = ((const float2*)(rep + (size_t)ri * ENT_DIM))[lane];
    float hd = h.x * hp.x + h.y * hp.y;
    float hs = h.x + h.y;
    float td = t.x * tp.x + t.y * tp.y;
    float ts = t.x + t.y;
    #pragma unroll
    for (int off = 32; off >= 1; off >>= 1) {
        hd += __shfl_xor(hd, off, 64);
        hs += __shfl_xor(hs, off, 64);
        td += __shfl_xor(td, off, 64);
        ts += __shfl_xor(ts, off, 64);
    }
    const float a = hd - td, c = hs - ts;
    const float dx = a * rp.x + c + r.x;
    const float dy = a * rp.y + c + r.y;
    float sc = dx * dx + dy * dy;
    #pragma unroll
    for (int off = 32; off >= 1; off >>= 1) sc += __shfl_xor(sc, off, 64);
    if (lane == 0) out[wave] = sc;
}

extern "C" void kernel_launch(void* const* d_in, const int* in_sizes, int n_in,
                              void* d_out, int out_size, void* d_ws, size_t ws_size,
                              hipStream_t stream) {
    const float* he  = (const float*)d_in[0];
    const float* hep = (const float*)d_in[1];
    const float* te  = (const float*)d_in[2];
    const float* tep = (const float*)d_in[3];
    const float* re  = (const float*)d_in[4];
    const float* rep = (const float*)d_in[5];
    const int* hidx  = (const int*)d_in[6];
    const int* tidx  = (const int*)d_in[7];
    const int* ridx  = (const int*)d_in[8];
    float* out = (float*)d_out;

    const int n_nodes = in_sizes[0] / ENT_DIM;   // 200000
    const int n_rels  = in_sizes[4] / ENT_DIM;   // 500
    const int B       = in_sizes[6];             // 500000

    const size_t hstats_bytes = (size_t)n_nodes * sizeof(float2);
    const size_t rstats_bytes = (size_t)n_rels * 8 * sizeof(float);
    const size_t need = 2 * hstats_bytes + rstats_bytes;
    const size_t lds_bytes = (size_t)n_rels * 9 * sizeof(float);

    if (ws_size >= need && lds_bytes <= 60 * 1024) {
        float2* hstats = (float2*)d_ws;
        float2* tstats = (float2*)((char*)d_ws + hstats_bytes);
        float*  rstats = (float*)((char*)d_ws + 2 * hstats_bytes);

        // Pass 1: 4 rows/wave per stream, 2 streams interleaved even/odd.
        const int nquads  = (n_nodes + 3) / 4;
        const int waves1  = 2 * nquads;
        const int blocks1 = (waves1 + 3) / 4;     // 4 waves per 256-thr block
        node_stats_kernel<<<blocks1, 256, 0, stream>>>(he, hep, te, tep,
                                                       hstats, tstats, n_nodes);
        // Pass 2
        const int blocks2 = (n_rels * 64 + 255) / 256;
        rel_stats_kernel<<<blocks2, 256, 0, stream>>>(re, rep, rstats, n_rels);
        // Pass 3: 2 elements per thread.
        const int nthreads = (B + 1) / 2;
        const int blocks3  = (nthreads + 255) / 256;
        score_kernel<<<blocks3, 256, lds_bytes, stream>>>(hidx, tidx, ridx,
                                                          hstats, tstats, rstats,
                                                          out, B, n_rels);
    } else {
        const int blocks = (B * 64 + 255) / 256;
        direct_kernel<<<blocks, 256, 0, stream>>>(he, hep, te, tep, re, rep,
                                                  hidx, tidx, ridx, out, B);
    }
}